// Round 1
// baseline (341.742 us; speedup 1.0000x reference)
//
#include <hip/hip_runtime.h>

#define NUM_LABELS 64
#define NWAVES 4   // 256 threads / 64-lane waves

// Phase 1: per-label sum + count via per-wave privatized LDS bins,
// then one global atomic per label per block.
__global__ __launch_bounds__(256) void tl_reduce(const float* __restrict__ tex,
                                                 const int* __restrict__ lab,
                                                 float* __restrict__ g_sums,
                                                 unsigned int* __restrict__ g_cnts,
                                                 int n) {
    __shared__ float s_sum[NWAVES][NUM_LABELS];
    __shared__ unsigned int s_cnt[NWAVES][NUM_LABELS];
    const int wave = threadIdx.x >> 6;

    for (int i = threadIdx.x; i < NWAVES * NUM_LABELS; i += 256) {
        (&s_sum[0][0])[i] = 0.0f;
        (&s_cnt[0][0])[i] = 0u;
    }
    __syncthreads();

    const int n4 = n >> 2;
    const float4* __restrict__ tex4 = (const float4*)tex;
    const int4* __restrict__ lab4 = (const int4*)lab;
    const int stride = gridDim.x * blockDim.x;

    for (int i = blockIdx.x * blockDim.x + threadIdx.x; i < n4; i += stride) {
        float4 t = tex4[i];
        int4 l = lab4[i];
        atomicAdd(&s_sum[wave][l.x], t.x); atomicAdd(&s_cnt[wave][l.x], 1u);
        atomicAdd(&s_sum[wave][l.y], t.y); atomicAdd(&s_cnt[wave][l.y], 1u);
        atomicAdd(&s_sum[wave][l.z], t.z); atomicAdd(&s_cnt[wave][l.z], 1u);
        atomicAdd(&s_sum[wave][l.w], t.w); atomicAdd(&s_cnt[wave][l.w], 1u);
    }

    // scalar tail (N % 4), handled once by block 0
    if (blockIdx.x == 0) {
        int base = n4 << 2;
        int rem = n - base;
        if ((int)threadIdx.x < rem) {
            int i = base + threadIdx.x;
            atomicAdd(&s_sum[wave][lab[i]], tex[i]);
            atomicAdd(&s_cnt[wave][lab[i]], 1u);
        }
    }
    __syncthreads();

    for (int l = threadIdx.x; l < NUM_LABELS; l += 256) {
        float s = 0.0f;
        unsigned int c = 0u;
        for (int w = 0; w < NWAVES; ++w) { s += s_sum[w][l]; c += s_cnt[w][l]; }
        if (c) {
            atomicAdd(&g_sums[l], s);      // device-scope by default
            atomicAdd(&g_cnts[l], c);
        }
    }
}

// Phase 2: build delta table in LDS (label 0 -> 0), apply out = tex - delta[lab].
__global__ __launch_bounds__(256) void tl_apply(const float* __restrict__ tex,
                                                const int* __restrict__ lab,
                                                const float* __restrict__ g_sums,
                                                const unsigned int* __restrict__ g_cnts,
                                                const float* __restrict__ intens,
                                                float* __restrict__ out, int n) {
    __shared__ float s_delta[NUM_LABELS];
    if (threadIdx.x < NUM_LABELS) {
        int l = threadIdx.x;
        float c = (float)g_cnts[l];
        float mean = g_sums[l] / fmaxf(c, 1.0f);
        s_delta[l] = (l > 0) ? (mean - intens[l]) : 0.0f;
    }
    __syncthreads();

    const int n4 = n >> 2;
    int i = blockIdx.x * blockDim.x + threadIdx.x;
    if (i < n4) {
        float4 t = ((const float4*)tex)[i];
        int4 l = ((const int4*)lab)[i];
        float4 o;
        o.x = t.x - s_delta[l.x & (NUM_LABELS - 1)];
        o.y = t.y - s_delta[l.y & (NUM_LABELS - 1)];
        o.z = t.z - s_delta[l.z & (NUM_LABELS - 1)];
        o.w = t.w - s_delta[l.w & (NUM_LABELS - 1)];
        ((float4*)out)[i] = o;
    }
    if (blockIdx.x == 0) {
        int base = n4 << 2;
        int rem = n - base;
        if ((int)threadIdx.x < rem) {
            int j = base + threadIdx.x;
            out[j] = tex[j] - s_delta[lab[j] & (NUM_LABELS - 1)];
        }
    }
}

extern "C" void kernel_launch(void* const* d_in, const int* in_sizes, int n_in,
                              void* d_out, int out_size, void* d_ws, size_t ws_size,
                              hipStream_t stream) {
    const float* tex    = (const float*)d_in[0];
    const int*   lab    = (const int*)d_in[1];
    const float* intens = (const float*)d_in[2];
    float* out = (float*)d_out;
    const int n = in_sizes[0];

    float* g_sums = (float*)d_ws;
    unsigned int* g_cnts = (unsigned int*)((char*)d_ws + NUM_LABELS * sizeof(float));

    // d_ws is re-poisoned to 0xAA before every timed launch — must zero each call.
    hipMemsetAsync(d_ws, 0, NUM_LABELS * (sizeof(float) + sizeof(unsigned int)), stream);

    // Phase 1: 2048 blocks (8/CU) grid-stride over float4s.
    tl_reduce<<<2048, 256, 0, stream>>>(tex, lab, g_sums, g_cnts, n);

    // Phase 2: one float4 per thread.
    const int n4 = n >> 2;
    const int blocks = (n4 + 255) / 256;
    tl_apply<<<blocks, 256, 0, stream>>>(tex, lab, g_sums, g_cnts, intens, out, n);
}